// Round 8
// baseline (417.355 us; speedup 1.0000x reference)
//
#include <hip/hip_runtime.h>

#define HH 256       // hidden size
#define NB 64        // batch (segments)
#define ROWS 128     // rows per block tile
#define NTOT 262144  // NK == NC
#define THREADS 256  // 4 waves

typedef _Float16 half8 __attribute__((ext_vector_type(8)));
typedef _Float16 half4 __attribute__((ext_vector_type(4)));
typedef float f32x4 __attribute__((ext_vector_type(4)));

// act LDS tile: [row][k] fp16, 128 rows x 256 k = 64KB, row stride 512B.
// XOR swizzle: reduces stride-512B row aliasing to 2-way.
__device__ __forceinline__ uint32_t swz(uint32_t r, uint32_t k) {
  return (((r << 9) + (k << 1)) ^ ((r & 7) << 4)) ^ ((r & 8) << 3);
}

// ---------------------------------------------------------------------------
// Heavy layer via MFMA, swapped operands: D[j][r] = sum_k WT[j][k]*act[r][k]
// Wave tile 64r x 128j (4 waves = 2 r-halves x 2 j-halves):
//  - B (act) reads: wave reads ONLY its 64-row slice = 32KB -> block LDS
//    reads = 128KB/layer (half of the 128rx64j shape).
//  - A (W): j-slice read by both r-partner waves back-to-back -> L1 catches
//    the second read; L2 sees ~128KB/block/layer.
// acc = 8jf x 4rf fragments (128 f32, lives in AGPRs).
// MODE: 0 = relu; 1 = plain (trunk c); 2 = multiply seg_mean[seg_g[r]] (branch)
// ---------------------------------------------------------------------------
template<int MODE>
__device__ __forceinline__ void heavy_layer(char* act, const _Float16* __restrict__ WT,
                                            const float* __restrict__ bias,
                                            const float* __restrict__ seg_mean,
                                            const int* __restrict__ seg_g, int tid)
{
  const int wid  = tid >> 6;
  const int lane = tid & 63;
  const int lr   = lane & 15;
  const int lg   = lane >> 4;
  const int r0   = (wid & 1) << 6;   // r-half
  const int j0   = (wid >> 1) << 7;  // j-half

  f32x4 acc[8][4];  // [jf][rf]
#pragma unroll
  for (int jf = 0; jf < 8; ++jf)
#pragma unroll
    for (int rf = 0; rf < 4; ++rf)
      acc[jf][rf] = (f32x4){0.f, 0.f, 0.f, 0.f};

  const _Float16* wbase = WT + (j0 + lr) * HH + lg * 8;

#pragma unroll 2
  for (int ks = 0; ks < 8; ++ks) {
    half8 b[4];
#pragma unroll
    for (int rf = 0; rf < 4; ++rf)
      b[rf] = *(const half8*)(act + swz(r0 + rf * 16 + lr, ks * 32 + lg * 8));
#pragma unroll
    for (int jf = 0; jf < 8; ++jf) {
      half8 a = *(const half8*)(wbase + jf * 16 * HH + ks * 32);
#pragma unroll
      for (int rf = 0; rf < 4; ++rf)
        acc[jf][rf] = __builtin_amdgcn_mfma_f32_16x16x32_f16(a, b[rf], acc[jf][rf], 0, 0, 0);
    }
  }

  __syncthreads();  // all waves done READING act before overwrite

  int sseg[4];
  if (MODE == 2) {
#pragma unroll
    for (int rf = 0; rf < 4; ++rf) sseg[rf] = seg_g[r0 + rf * 16 + lr];
  }

#pragma unroll
  for (int jf = 0; jf < 8; ++jf) {
    f32x4 bj = *(const f32x4*)(bias + j0 + jf * 16 + lg * 4);
#pragma unroll
    for (int rf = 0; rf < 4; ++rf) {
      f32x4 v = acc[jf][rf] + bj;
      if (MODE == 2) {
        f32x4 sm = *(const f32x4*)(seg_mean + sseg[rf] * HH + j0 + jf * 16 + lg * 4);
        v *= sm;
      }
      half4 h;
#pragma unroll
      for (int u = 0; u < 4; ++u) {
        float x = v[u];
        if (MODE == 0) x = fmaxf(x, 0.f);
        h[u] = (_Float16)x;
      }
      *(half4*)(act + swz(r0 + rf * 16 + lr, j0 + jf * 16 + lg * 4)) = h;
    }
  }
  __syncthreads();
}

// layer 1 via MFMA: F=3 -> H (relu), K padded 3 -> 32 with zeros.
// x read directly from global (lg==0 lanes, L1-cached).
__device__ __forceinline__ void layer1_mfma(char* act, const float* __restrict__ x,
                                            int r0g, const float* __restrict__ W0,
                                            const float* __restrict__ b0, int tid)
{
  const int wid  = tid >> 6;
  const int lane = tid & 63;
  const int lr   = lane & 15;
  const int lg   = lane >> 4;
  const int r0   = (wid & 1) << 6;
  const int j0   = (wid >> 1) << 7;

  half8 a[8];
#pragma unroll
  for (int jf = 0; jf < 8; ++jf) {
    half8 v = {0, 0, 0, 0, 0, 0, 0, 0};
    if (lg == 0) {
      int j = j0 + jf * 16 + lr;
      v[0] = (_Float16)W0[j];
      v[1] = (_Float16)W0[HH + j];
      v[2] = (_Float16)W0[2 * HH + j];
    }
    a[jf] = v;
  }

  f32x4 acc[8][4];
#pragma unroll
  for (int jf = 0; jf < 8; ++jf)
#pragma unroll
    for (int rf = 0; rf < 4; ++rf)
      acc[jf][rf] = (f32x4){0.f, 0.f, 0.f, 0.f};

#pragma unroll
  for (int rf = 0; rf < 4; ++rf) {
    half8 b = {0, 0, 0, 0, 0, 0, 0, 0};
    if (lg == 0) {
      const float* xp = x + (size_t)(r0g + r0 + rf * 16 + lr) * 3;
      b[0] = (_Float16)xp[0];
      b[1] = (_Float16)xp[1];
      b[2] = (_Float16)xp[2];
    }
#pragma unroll
    for (int jf = 0; jf < 8; ++jf)
      acc[jf][rf] = __builtin_amdgcn_mfma_f32_16x16x32_f16(a[jf], b, acc[jf][rf], 0, 0, 0);
  }

#pragma unroll
  for (int jf = 0; jf < 8; ++jf) {
    f32x4 bj = *(const f32x4*)(b0 + j0 + jf * 16 + lg * 4);
#pragma unroll
    for (int rf = 0; rf < 4; ++rf) {
      f32x4 v = acc[jf][rf] + bj;
      half4 h;
#pragma unroll
      for (int u = 0; u < 4; ++u)
        h[u] = (_Float16)fmaxf(v[u], 0.f);
      *(half4*)(act + swz(r0 + rf * 16 + lr, j0 + jf * 16 + lg * 4)) = h;
    }
  }
  __syncthreads();
}

// ---------------------------------------------------------------------------
__global__ __launch_bounds__(THREADS, 2)
void trunk_kernel(const float* __restrict__ nodes, const int* __restrict__ coord_seg,
                  const float* __restrict__ tw0, const float* __restrict__ tb0,
                  const _Float16* __restrict__ wt1, const float* __restrict__ tb1,
                  const _Float16* __restrict__ wt2, const float* __restrict__ tb2,
                  float* __restrict__ seg_sum)
{
  __shared__ __align__(16) char act[ROWS * HH * 2];  // 64KB
  const int tid = threadIdx.x;
  const int r0g = blockIdx.x * ROWS;

  layer1_mfma(act, nodes, r0g, tw0, tb0, tid);
  heavy_layer<0>(act, wt1, tb1, nullptr, nullptr, tid);
  heavy_layer<1>(act, wt2, tb2, nullptr, nullptr, tid);  // c (no relu)

  // per-segment sums of c; segs sorted -> most tiles single-segment.
  {
    const int j = tid;
    const int s_lo = coord_seg[r0g];
    const int s_hi = coord_seg[r0g + ROWS - 1];
    if (s_lo == s_hi) {
      float p = 0.f;
#pragma unroll 8
      for (int r = 0; r < ROWS; ++r)
        p += (float)*(const _Float16*)(act + swz(r, j));
      atomicAdd(&seg_sum[s_lo * HH + j], p);
    } else {
      for (int s = s_lo; s <= s_hi; ++s) {
        float p = 0.f;
        for (int r = 0; r < ROWS; ++r)
          if (coord_seg[r0g + r] == s)
            p += (float)*(const _Float16*)(act + swz(r, j));
        atomicAdd(&seg_sum[s * HH + j], p);
      }
    }
  }
}

__global__ __launch_bounds__(THREADS, 2)
void branch_kernel(const float* __restrict__ known_nodes, const int* __restrict__ known_seg,
                   const float* __restrict__ bw0, const float* __restrict__ bb0,
                   const _Float16* __restrict__ wt1, const float* __restrict__ bb1,
                   const _Float16* __restrict__ wt2, const float* __restrict__ bb2,
                   const float* __restrict__ seg_mean,
                   const _Float16* __restrict__ wto, const float* __restrict__ ob0,
                   const float* __restrict__ ow1, const float* __restrict__ ob1,
                   float* __restrict__ out)
{
  __shared__ __align__(16) char act[ROWS * HH * 2];  // 64KB
  __shared__ float ps[2 * ROWS * 3];                 // tail partials, 3KB
  const int tid = threadIdx.x;
  const int r0g = blockIdx.x * ROWS;

  layer1_mfma(act, known_nodes, r0g, bw0, bb0, tid);
  heavy_layer<0>(act, wt1, bb1, nullptr, nullptr, tid);
  heavy_layer<2>(act, wt2, bb2, seg_mean, known_seg + r0g, tid);  // f*seg_mean
  heavy_layer<0>(act, wto, ob0, nullptr, nullptr, tid);           // relu(.@ow0+ob0)

  // out = h @ ow1 + ob1 (256 -> 3): 256 threads, 2 k-halves in parallel
  {
    const int r = tid & 127;
    const int q = tid >> 7;
    float o0 = 0.f, o1 = 0.f, o2 = 0.f;
    for (int kk = 0; kk < 128; kk += 8) {
      int k0 = q * 128 + kk;
      half8 h = *(const half8*)(act + swz(r, k0));
#pragma unroll
      for (int u = 0; u < 8; ++u) {
        float a = (float)h[u];
        o0 = fmaf(a, ow1[(k0 + u) * 3 + 0], o0);
        o1 = fmaf(a, ow1[(k0 + u) * 3 + 1], o1);
        o2 = fmaf(a, ow1[(k0 + u) * 3 + 2], o2);
      }
    }
    float* p = ps + q * ROWS * 3;
    p[r * 3 + 0] = o0; p[r * 3 + 1] = o1; p[r * 3 + 2] = o2;
  }
  __syncthreads();
  if (tid < ROWS) {
    const int r = tid;
    float* dst = out + (size_t)(r0g + r) * 3;
#pragma unroll
    for (int c = 0; c < 3; ++c)
      dst[c] = ob1[c] + ps[r * 3 + c] + ps[ROWS * 3 + r * 3 + c];
  }
}

// W[256][256] fp32 row-major -> WT[j][k] fp16 (5 matrices), once per launch.
struct WPtrs { const float* w[5]; _Float16* wt[5]; };
__global__ void transpose_kernel(WPtrs p)
{
  const int m = blockIdx.x >> 8;   // matrix
  const int j = blockIdx.x & 255;  // output row
  const int k = threadIdx.x;       // 256 threads, coalesced writes
  p.wt[m][j * HH + k] = (_Float16)p.w[m][k * HH + j];
}

__global__ void zero_kernel(float* __restrict__ p, int n)
{
  int i = blockIdx.x * blockDim.x + threadIdx.x;
  if (i < n) p[i] = 0.f;
}

__global__ void mean_kernel(const float* __restrict__ seg_sum,
                            const int* __restrict__ coord_seg,
                            float* __restrict__ seg_mean)
{
  const int b = blockIdx.x;
  int lo = 0, n = NTOT;
  while (n > 0) { int h = n >> 1; int mid = lo + h;
    if (coord_seg[mid] < b) { lo = mid + 1; n -= h + 1; } else n = h; }
  int hi = lo; n = NTOT - lo;
  while (n > 0) { int h = n >> 1; int mid = hi + h;
    if (coord_seg[mid] < b + 1) { hi = mid + 1; n -= h + 1; } else n = h; }
  float inv = 1.0f / fmaxf((float)(hi - lo), 1.0f);
  seg_mean[b * HH + threadIdx.x] = seg_sum[b * HH + threadIdx.x] * inv;
}

// ---------------------------------------------------------------------------
extern "C" void kernel_launch(void* const* d_in, const int* in_sizes, int n_in,
                              void* d_out, int out_size, void* d_ws, size_t ws_size,
                              hipStream_t stream)
{
  const float* known_nodes = (const float*)d_in[0];
  const float* nodes       = (const float*)d_in[1];
  const int*   known_seg   = (const int*)d_in[2];
  const int*   coord_seg   = (const int*)d_in[3];
  const float* bw0 = (const float*)d_in[4];
  const float* bb0 = (const float*)d_in[5];
  const float* bw1 = (const float*)d_in[6];
  const float* bb1 = (const float*)d_in[7];
  const float* bw2 = (const float*)d_in[8];
  const float* bb2 = (const float*)d_in[9];
  const float* tw0 = (const float*)d_in[10];
  const float* tb0 = (const float*)d_in[11];
  const float* tw1 = (const float*)d_in[12];
  const float* tb1 = (const float*)d_in[13];
  const float* tw2 = (const float*)d_in[14];
  const float* tb2 = (const float*)d_in[15];
  const float* ow0 = (const float*)d_in[16];
  const float* ob0 = (const float*)d_in[17];
  const float* ow1 = (const float*)d_in[18];
  const float* ob1 = (const float*)d_in[19];

  float* out      = (float*)d_out;
  float* seg_sum  = (float*)d_ws;                        // [64][256] f32
  float* seg_mean = seg_sum + NB * HH;                   // [64][256] f32
  _Float16* wtb   = (_Float16*)((char*)d_ws + (size_t)2 * NB * HH * 4);
  _Float16* wt_tw1 = wtb + 0 * HH * HH;
  _Float16* wt_tw2 = wtb + 1 * HH * HH;
  _Float16* wt_bw1 = wtb + 2 * HH * HH;
  _Float16* wt_bw2 = wtb + 3 * HH * HH;
  _Float16* wt_ow0 = wtb + 4 * HH * HH;

  WPtrs wp;
  wp.w[0] = tw1; wp.wt[0] = wt_tw1;
  wp.w[1] = tw2; wp.wt[1] = wt_tw2;
  wp.w[2] = bw1; wp.wt[2] = wt_bw1;
  wp.w[3] = bw2; wp.wt[3] = wt_bw2;
  wp.w[4] = ow0; wp.wt[4] = wt_ow0;

  transpose_kernel<<<5 * 256, 256, 0, stream>>>(wp);
  zero_kernel<<<(NB * HH + 255) / 256, 256, 0, stream>>>(seg_sum, NB * HH);
  trunk_kernel<<<NTOT / ROWS, THREADS, 0, stream>>>(nodes, coord_seg,
                                                    tw0, tb0, wt_tw1, tb1, wt_tw2, tb2,
                                                    seg_sum);
  mean_kernel<<<NB, 256, 0, stream>>>(seg_sum, coord_seg, seg_mean);
  branch_kernel<<<NTOT / ROWS, THREADS, 0, stream>>>(known_nodes, known_seg,
                                                     bw0, bb0, wt_bw1, bb1, wt_bw2, bb2,
                                                     seg_mean,
                                                     wt_ow0, ob0, ow1, ob1,
                                                     out);
}

// Round 9
// 403.317 us; speedup vs baseline: 1.0348x; 1.0348x over previous
//
#include <hip/hip_runtime.h>

#define HH 256       // hidden size
#define NB 64        // batch (segments)
#define ROWS 128     // rows per block tile
#define NTOT 262144  // NK == NC
#define THREADS 512  // 8 waves = 2 r-halves x 4 j-quarters

typedef _Float16 half8 __attribute__((ext_vector_type(8)));
typedef _Float16 half4 __attribute__((ext_vector_type(4)));
typedef float f32x4 __attribute__((ext_vector_type(4)));

// act LDS tile: [row][k] fp16, 128 rows x 256 k = 64KB, row stride 512B.
// XOR swizzle: reduces stride-512B row aliasing to 2-way.
__device__ __forceinline__ uint32_t swz(uint32_t r, uint32_t k) {
  return (((r << 9) + (k << 1)) ^ ((r & 7) << 4)) ^ ((r & 8) << 3);
}

// ---------------------------------------------------------------------------
// Heavy layer via MFMA, swapped operands: D[j][r] = sum_k WT[j][k]*act[r][k]
// 8 waves: wid = (jq<<1)|rh -> wave tile 64r x 64j (R4/R7-PROVEN no-spill
// shape: acc[4][4], unroll 2, ONE a-frag live inside the jf loop).
//  - j-quarters disjoint across wave pairs -> block reads W exactly once.
//  - r-partner waves read the same W addresses back-to-back -> L1 hit.
//  - 2 blocks/CU x 8 waves = 4 waves/SIMD (R4-level TLP).
// MODE: 0 = relu; 1 = plain (trunk c); 2 = multiply seg_mean[seg_g[r]] (branch)
// ---------------------------------------------------------------------------
template<int MODE>
__device__ __forceinline__ void heavy_layer(char* act, const _Float16* __restrict__ WT,
                                            const float* __restrict__ bias,
                                            const float* __restrict__ seg_mean,
                                            const int* __restrict__ seg_g, int tid)
{
  const int wid  = tid >> 6;
  const int lane = tid & 63;
  const int lr   = lane & 15;
  const int lg   = lane >> 4;
  const int r0   = (wid & 1) << 6;   // r-half
  const int j0   = (wid >> 1) << 6;  // j-quarter

  f32x4 acc[4][4];  // [jf][rf]
#pragma unroll
  for (int jf = 0; jf < 4; ++jf)
#pragma unroll
    for (int rf = 0; rf < 4; ++rf)
      acc[jf][rf] = (f32x4){0.f, 0.f, 0.f, 0.f};

  const _Float16* wbase = WT + (j0 + lr) * HH + lg * 8;

#pragma unroll 2
  for (int ks = 0; ks < 8; ++ks) {
    half8 b[4];
#pragma unroll
    for (int rf = 0; rf < 4; ++rf)
      b[rf] = *(const half8*)(act + swz(r0 + rf * 16 + lr, ks * 32 + lg * 8));
#pragma unroll
    for (int jf = 0; jf < 4; ++jf) {
      half8 a = *(const half8*)(wbase + jf * 16 * HH + ks * 32);
#pragma unroll
      for (int rf = 0; rf < 4; ++rf)
        acc[jf][rf] = __builtin_amdgcn_mfma_f32_16x16x32_f16(a, b[rf], acc[jf][rf], 0, 0, 0);
    }
  }

  __syncthreads();  // all waves done READING act before overwrite

  int sseg[4];
  if (MODE == 2) {
#pragma unroll
    for (int rf = 0; rf < 4; ++rf) sseg[rf] = seg_g[r0 + rf * 16 + lr];
  }

#pragma unroll
  for (int jf = 0; jf < 4; ++jf) {
    f32x4 bj = *(const f32x4*)(bias + j0 + jf * 16 + lg * 4);
#pragma unroll
    for (int rf = 0; rf < 4; ++rf) {
      f32x4 v = acc[jf][rf] + bj;
      if (MODE == 2) {
        f32x4 sm = *(const f32x4*)(seg_mean + sseg[rf] * HH + j0 + jf * 16 + lg * 4);
        v *= sm;
      }
      half4 h;
#pragma unroll
      for (int u = 0; u < 4; ++u) {
        float x = v[u];
        if (MODE == 0) x = fmaxf(x, 0.f);
        h[u] = (_Float16)x;
      }
      *(half4*)(act + swz(r0 + rf * 16 + lr, j0 + jf * 16 + lg * 4)) = h;
    }
  }
  __syncthreads();
}

// layer 1 via MFMA: F=3 -> H (relu), K padded 3 -> 32 with zeros.
// x read directly from global (lg==0 lanes, L1-cached).
__device__ __forceinline__ void layer1_mfma(char* act, const float* __restrict__ x,
                                            int r0g, const float* __restrict__ W0,
                                            const float* __restrict__ b0, int tid)
{
  const int wid  = tid >> 6;
  const int lane = tid & 63;
  const int lr   = lane & 15;
  const int lg   = lane >> 4;
  const int r0   = (wid & 1) << 6;
  const int j0   = (wid >> 1) << 6;

  half8 a[4];
#pragma unroll
  for (int jf = 0; jf < 4; ++jf) {
    half8 v = {0, 0, 0, 0, 0, 0, 0, 0};
    if (lg == 0) {
      int j = j0 + jf * 16 + lr;
      v[0] = (_Float16)W0[j];
      v[1] = (_Float16)W0[HH + j];
      v[2] = (_Float16)W0[2 * HH + j];
    }
    a[jf] = v;
  }

  f32x4 acc[4][4];
#pragma unroll
  for (int jf = 0; jf < 4; ++jf)
#pragma unroll
    for (int rf = 0; rf < 4; ++rf)
      acc[jf][rf] = (f32x4){0.f, 0.f, 0.f, 0.f};

#pragma unroll
  for (int rf = 0; rf < 4; ++rf) {
    half8 b = {0, 0, 0, 0, 0, 0, 0, 0};
    if (lg == 0) {
      const float* xp = x + (size_t)(r0g + r0 + rf * 16 + lr) * 3;
      b[0] = (_Float16)xp[0];
      b[1] = (_Float16)xp[1];
      b[2] = (_Float16)xp[2];
    }
#pragma unroll
    for (int jf = 0; jf < 4; ++jf)
      acc[jf][rf] = __builtin_amdgcn_mfma_f32_16x16x32_f16(a[jf], b, acc[jf][rf], 0, 0, 0);
  }

#pragma unroll
  for (int jf = 0; jf < 4; ++jf) {
    f32x4 bj = *(const f32x4*)(b0 + j0 + jf * 16 + lg * 4);
#pragma unroll
    for (int rf = 0; rf < 4; ++rf) {
      f32x4 v = acc[jf][rf] + bj;
      half4 h;
#pragma unroll
      for (int u = 0; u < 4; ++u)
        h[u] = (_Float16)fmaxf(v[u], 0.f);
      *(half4*)(act + swz(r0 + rf * 16 + lr, j0 + jf * 16 + lg * 4)) = h;
    }
  }
  __syncthreads();
}

// ---------------------------------------------------------------------------
__global__ __launch_bounds__(THREADS, 4)
void trunk_kernel(const float* __restrict__ nodes, const int* __restrict__ coord_seg,
                  const float* __restrict__ tw0, const float* __restrict__ tb0,
                  const _Float16* __restrict__ wt1, const float* __restrict__ tb1,
                  const _Float16* __restrict__ wt2, const float* __restrict__ tb2,
                  float* __restrict__ seg_sum)
{
  __shared__ __align__(16) char act[ROWS * HH * 2];  // 64KB
  const int tid = threadIdx.x;
  const int r0g = blockIdx.x * ROWS;

  layer1_mfma(act, nodes, r0g, tw0, tb0, tid);
  heavy_layer<0>(act, wt1, tb1, nullptr, nullptr, tid);
  heavy_layer<1>(act, wt2, tb2, nullptr, nullptr, tid);  // c (no relu)

  // per-segment sums of c; 512 threads: j = tid&255, half = tid>>8 (64 rows).
  {
    const int j  = tid & 255;
    const int rb = (tid >> 8) * 64;
    const int s_lo = coord_seg[r0g + rb];
    const int s_hi = coord_seg[r0g + rb + 63];
    if (s_lo == s_hi) {
      float p = 0.f;
#pragma unroll 8
      for (int rr = 0; rr < 64; ++rr)
        p += (float)*(const _Float16*)(act + swz(rb + rr, j));
      atomicAdd(&seg_sum[s_lo * HH + j], p);
    } else {
      for (int s = s_lo; s <= s_hi; ++s) {
        float p = 0.f;
        for (int rr = 0; rr < 64; ++rr)
          if (coord_seg[r0g + rb + rr] == s)
            p += (float)*(const _Float16*)(act + swz(rb + rr, j));
        atomicAdd(&seg_sum[s * HH + j], p);
      }
    }
  }
}

__global__ __launch_bounds__(THREADS, 4)
void branch_kernel(const float* __restrict__ known_nodes, const int* __restrict__ known_seg,
                   const float* __restrict__ bw0, const float* __restrict__ bb0,
                   const _Float16* __restrict__ wt1, const float* __restrict__ bb1,
                   const _Float16* __restrict__ wt2, const float* __restrict__ bb2,
                   const float* __restrict__ seg_mean,
                   const _Float16* __restrict__ wto, const float* __restrict__ ob0,
                   const float* __restrict__ ow1, const float* __restrict__ ob1,
                   float* __restrict__ out)
{
  __shared__ __align__(16) char act[ROWS * HH * 2];  // 64KB
  __shared__ float ps[4 * ROWS * 3];                 // tail partials, 6KB
  const int tid = threadIdx.x;
  const int r0g = blockIdx.x * ROWS;

  layer1_mfma(act, known_nodes, r0g, bw0, bb0, tid);
  heavy_layer<0>(act, wt1, bb1, nullptr, nullptr, tid);
  heavy_layer<2>(act, wt2, bb2, seg_mean, known_seg + r0g, tid);  // f*seg_mean
  heavy_layer<0>(act, wto, ob0, nullptr, nullptr, tid);           // relu(.@ow0+ob0)

  // out = h @ ow1 + ob1 (256 -> 3): 512 threads, 4 k-quarters in parallel
  {
    const int r = tid & 127;
    const int q = tid >> 7;
    float o0 = 0.f, o1 = 0.f, o2 = 0.f;
    for (int kk = 0; kk < 64; kk += 8) {
      int k0 = q * 64 + kk;
      half8 h = *(const half8*)(act + swz(r, k0));
#pragma unroll
      for (int u = 0; u < 8; ++u) {
        float a = (float)h[u];
        o0 = fmaf(a, ow1[(k0 + u) * 3 + 0], o0);
        o1 = fmaf(a, ow1[(k0 + u) * 3 + 1], o1);
        o2 = fmaf(a, ow1[(k0 + u) * 3 + 2], o2);
      }
    }
    float* p = ps + q * ROWS * 3;
    p[r * 3 + 0] = o0; p[r * 3 + 1] = o1; p[r * 3 + 2] = o2;
  }
  __syncthreads();
  if (tid < ROWS) {
    const int r = tid;
    float* dst = out + (size_t)(r0g + r) * 3;
#pragma unroll
    for (int c = 0; c < 3; ++c) {
      float o = ob1[c];
#pragma unroll
      for (int q = 0; q < 4; ++q) o += ps[q * ROWS * 3 + r * 3 + c];
      dst[c] = o;
    }
  }
}

// W[256][256] fp32 row-major -> WT[j][k] fp16 (5 matrices), once per launch.
struct WPtrs { const float* w[5]; _Float16* wt[5]; };
__global__ void transpose_kernel(WPtrs p)
{
  const int m = blockIdx.x >> 8;   // matrix
  const int j = blockIdx.x & 255;  // output row
  const int k = threadIdx.x;       // 256 threads, coalesced writes
  p.wt[m][j * HH + k] = (_Float16)p.w[m][k * HH + j];
}

__global__ void zero_kernel(float* __restrict__ p, int n)
{
  int i = blockIdx.x * blockDim.x + threadIdx.x;
  if (i < n) p[i] = 0.f;
}

__global__ void mean_kernel(const float* __restrict__ seg_sum,
                            const int* __restrict__ coord_seg,
                            float* __restrict__ seg_mean)
{
  const int b = blockIdx.x;
  int lo = 0, n = NTOT;
  while (n > 0) { int h = n >> 1; int mid = lo + h;
    if (coord_seg[mid] < b) { lo = mid + 1; n -= h + 1; } else n = h; }
  int hi = lo; n = NTOT - lo;
  while (n > 0) { int h = n >> 1; int mid = hi + h;
    if (coord_seg[mid] < b + 1) { hi = mid + 1; n -= h + 1; } else n = h; }
  float inv = 1.0f / fmaxf((float)(hi - lo), 1.0f);
  seg_mean[b * HH + threadIdx.x] = seg_sum[b * HH + threadIdx.x] * inv;
}

// ---------------------------------------------------------------------------
extern "C" void kernel_launch(void* const* d_in, const int* in_sizes, int n_in,
                              void* d_out, int out_size, void* d_ws, size_t ws_size,
                              hipStream_t stream)
{
  const float* known_nodes = (const float*)d_in[0];
  const float* nodes       = (const float*)d_in[1];
  const int*   known_seg   = (const int*)d_in[2];
  const int*   coord_seg   = (const int*)d_in[3];
  const float* bw0 = (const float*)d_in[4];
  const float* bb0 = (const float*)d_in[5];
  const float* bw1 = (const float*)d_in[6];
  const float* bb1 = (const float*)d_in[7];
  const float* bw2 = (const float*)d_in[8];
  const float* bb2 = (const float*)d_in[9];
  const float* tw0 = (const float*)d_in[10];
  const float* tb0 = (const float*)d_in[11];
  const float* tw1 = (const float*)d_in[12];
  const float* tb1 = (const float*)d_in[13];
  const float* tw2 = (const float*)d_in[14];
  const float* tb2 = (const float*)d_in[15];
  const float* ow0 = (const float*)d_in[16];
  const float* ob0 = (const float*)d_in[17];
  const float* ow1 = (const float*)d_in[18];
  const float* ob1 = (const float*)d_in[19];

  float* out      = (float*)d_out;
  float* seg_sum  = (float*)d_ws;                        // [64][256] f32
  float* seg_mean = seg_sum + NB * HH;                   // [64][256] f32
  _Float16* wtb   = (_Float16*)((char*)d_ws + (size_t)2 * NB * HH * 4);
  _Float16* wt_tw1 = wtb + 0 * HH * HH;
  _Float16* wt_tw2 = wtb + 1 * HH * HH;
  _Float16* wt_bw1 = wtb + 2 * HH * HH;
  _Float16* wt_bw2 = wtb + 3 * HH * HH;
  _Float16* wt_ow0 = wtb + 4 * HH * HH;

  WPtrs wp;
  wp.w[0] = tw1; wp.wt[0] = wt_tw1;
  wp.w[1] = tw2; wp.wt[1] = wt_tw2;
  wp.w[2] = bw1; wp.wt[2] = wt_bw1;
  wp.w[3] = bw2; wp.wt[3] = wt_bw2;
  wp.w[4] = ow0; wp.wt[4] = wt_ow0;

  transpose_kernel<<<5 * 256, 256, 0, stream>>>(wp);
  zero_kernel<<<(NB * HH + 255) / 256, 256, 0, stream>>>(seg_sum, NB * HH);
  trunk_kernel<<<NTOT / ROWS, THREADS, 0, stream>>>(nodes, coord_seg,
                                                    tw0, tb0, wt_tw1, tb1, wt_tw2, tb2,
                                                    seg_sum);
  mean_kernel<<<NB, 256, 0, stream>>>(seg_sum, coord_seg, seg_mean);
  branch_kernel<<<NTOT / ROWS, THREADS, 0, stream>>>(known_nodes, known_seg,
                                                     bw0, bb0, wt_bw1, bb1, wt_bw2, bb2,
                                                     seg_mean,
                                                     wt_ow0, ob0, ow1, ob1,
                                                     out);
}

// Round 10
// 266.298 us; speedup vs baseline: 1.5673x; 1.5145x over previous
//
#include <hip/hip_runtime.h>

#define HH 256       // hidden size
#define NB 64        // batch (segments)
#define ROWS 64      // rows per block tile
#define NTOT 262144  // NK == NC
#define THREADS 256  // 4 waves
#define PANB 16384   // one W k-panel: 256 j x 32 k x 2B = 16KB

typedef _Float16 half8 __attribute__((ext_vector_type(8)));
typedef _Float16 half4 __attribute__((ext_vector_type(4)));
typedef float f32x4 __attribute__((ext_vector_type(4)));

typedef __attribute__((address_space(1))) const void gas_t;
typedef __attribute__((address_space(3))) void las_t;

// act LDS tile: [row][k] fp16, 64 rows x 256 k = 32KB, row stride 512B.
__device__ __forceinline__ uint32_t swz(uint32_t r, uint32_t k) {
  return (((r << 9) + (k << 1)) ^ ((r & 7) << 4)) ^ ((r & 8) << 3);
}

// Stage one 16KB W k-panel: wave wid copies its 4KB slab (identity copy,
// WT2 is pre-arranged in panel-linear layout). 4 DMA calls x 1KB per wave.
__device__ __forceinline__ void stage_panel(const char* __restrict__ g, char* l,
                                            int wid, int lane)
{
  const char* gp = g + wid * 4096 + lane * 16;
  char* lp = l + wid * 4096;
#pragma unroll
  for (int c = 0; c < 4; ++c)
    __builtin_amdgcn_global_load_lds((gas_t*)(gp + c * 1024), (las_t*)(lp + c * 1024),
                                     16, 0, 0);
}

// ---------------------------------------------------------------------------
// Heavy layer via MFMA, swapped operands: D[j][r] = sum_k WT[j][k]*act[r][k]
// A now comes from LDS panels staged by async DMA (double-buffered, counted
// vmcnt waits, raw barriers -> prefetch queue never drained mid-layer).
// Panel layout: pan[g=0..3][j=0..255][16B] ; A-read: lane(lr,lg) ->
//   pan + lg*4096 + (j0+jf*16+lr)*16  (2-way bank alias = free).
// MODE: 0 relu; 1 plain (trunk c); 2 multiply seg_mean[seg_g[r]] (branch)
// ---------------------------------------------------------------------------
template<int MODE>
__device__ __forceinline__ void heavy_layer(char* act, char* wpan,
                                            const char* __restrict__ wt2,
                                            const float* __restrict__ bias,
                                            const float* __restrict__ seg_mean,
                                            const int* __restrict__ seg_g, int tid)
{
  const int wid  = tid >> 6;
  const int lane = tid & 63;
  const int lr   = lane & 15;
  const int lg   = lane >> 4;
  const int j0   = wid << 6;

  f32x4 acc[4][4];  // [jf][rf]
#pragma unroll
  for (int jf = 0; jf < 4; ++jf)
#pragma unroll
    for (int rf = 0; rf < 4; ++rf)
      acc[jf][rf] = (f32x4){0.f, 0.f, 0.f, 0.f};

  // prologue: stage panels 0 and 1 (8 calls in flight per wave)
  stage_panel(wt2 + 0 * PANB, wpan + 0 * PANB, wid, lane);
  stage_panel(wt2 + 1 * PANB, wpan + 1 * PANB, wid, lane);

#pragma unroll
  for (int ks = 0; ks < 8; ++ks) {
    char* cur = wpan + (ks & 1) * PANB;
    // wait for own slab of panel ks (stage(ks+1)'s 4 calls may remain)
    if (ks < 7) asm volatile("s_waitcnt vmcnt(4)" ::: "memory");
    else        asm volatile("s_waitcnt vmcnt(0)" ::: "memory");
    __builtin_amdgcn_sched_barrier(0);
    __builtin_amdgcn_s_barrier();  // all waves' slabs of panel ks visible

    half8 b[4];
#pragma unroll
    for (int rf = 0; rf < 4; ++rf)
      b[rf] = *(const half8*)(act + swz(rf * 16 + lr, ks * 32 + lg * 8));
#pragma unroll
    for (int jf = 0; jf < 4; ++jf) {
      half8 a = *(const half8*)(cur + lg * 4096 + (j0 + jf * 16 + lr) * 16);
#pragma unroll
      for (int rf = 0; rf < 4; ++rf)
        acc[jf][rf] = __builtin_amdgcn_mfma_f32_16x16x32_f16(a, b[rf], acc[jf][rf], 0, 0, 0);
    }
    // MFMAs above forced lgkm completion of this wave's panel reads.
    __builtin_amdgcn_s_barrier();  // all waves done reading panel ks
    if (ks < 6)
      stage_panel(wt2 + (ks + 2) * PANB, cur, wid, lane);  // reuse freed buffer
  }
  // here: all DMAs retired (vmcnt 0 at ks=7), all act reads done.

  int sseg[4];
  if (MODE == 2) {
#pragma unroll
    for (int rf = 0; rf < 4; ++rf) sseg[rf] = seg_g[rf * 16 + lr];
  }

#pragma unroll
  for (int jf = 0; jf < 4; ++jf) {
    f32x4 bj = *(const f32x4*)(bias + j0 + jf * 16 + lg * 4);
#pragma unroll
    for (int rf = 0; rf < 4; ++rf) {
      f32x4 v = acc[jf][rf] + bj;
      if (MODE == 2) {
        f32x4 sm = *(const f32x4*)(seg_mean + sseg[rf] * HH + j0 + jf * 16 + lg * 4);
        v *= sm;
      }
      half4 h;
#pragma unroll
      for (int u = 0; u < 4; ++u) {
        float x = v[u];
        if (MODE == 0) x = fmaxf(x, 0.f);
        h[u] = (_Float16)x;
      }
      *(half4*)(act + swz(rf * 16 + lr, j0 + jf * 16 + lg * 4)) = h;
    }
  }
  __syncthreads();  // act tile complete for next layer (queue already empty)
}

// layer 1 via MFMA: F=3 -> H (relu), K padded 3 -> 32 with zeros.
__device__ __forceinline__ void layer1_mfma(char* act, const float* __restrict__ x,
                                            int r0g, const float* __restrict__ W0,
                                            const float* __restrict__ b0, int tid)
{
  const int wid  = tid >> 6;
  const int lane = tid & 63;
  const int lr   = lane & 15;
  const int lg   = lane >> 4;
  const int j0   = wid << 6;

  half8 a[4];
#pragma unroll
  for (int jf = 0; jf < 4; ++jf) {
    half8 v = {0, 0, 0, 0, 0, 0, 0, 0};
    if (lg == 0) {
      int j = j0 + jf * 16 + lr;
      v[0] = (_Float16)W0[j];
      v[1] = (_Float16)W0[HH + j];
      v[2] = (_Float16)W0[2 * HH + j];
    }
    a[jf] = v;
  }

  f32x4 acc[4][4];
#pragma unroll
  for (int jf = 0; jf < 4; ++jf)
#pragma unroll
    for (int rf = 0; rf < 4; ++rf)
      acc[jf][rf] = (f32x4){0.f, 0.f, 0.f, 0.f};

#pragma unroll
  for (int rf = 0; rf < 4; ++rf) {
    half8 b = {0, 0, 0, 0, 0, 0, 0, 0};
    if (lg == 0) {
      const float* xp = x + (size_t)(r0g + rf * 16 + lr) * 3;
      b[0] = (_Float16)xp[0];
      b[1] = (_Float16)xp[1];
      b[2] = (_Float16)xp[2];
    }
#pragma unroll
    for (int jf = 0; jf < 4; ++jf)
      acc[jf][rf] = __builtin_amdgcn_mfma_f32_16x16x32_f16(a[jf], b, acc[jf][rf], 0, 0, 0);
  }

#pragma unroll
  for (int jf = 0; jf < 4; ++jf) {
    f32x4 bj = *(const f32x4*)(b0 + j0 + jf * 16 + lg * 4);
#pragma unroll
    for (int rf = 0; rf < 4; ++rf) {
      f32x4 v = acc[jf][rf] + bj;
      half4 h;
#pragma unroll
      for (int u = 0; u < 4; ++u)
        h[u] = (_Float16)fmaxf(v[u], 0.f);
      *(half4*)(act + swz(rf * 16 + lr, j0 + jf * 16 + lg * 4)) = h;
    }
  }
  __syncthreads();
}

// ---------------------------------------------------------------------------
__global__ __launch_bounds__(THREADS, 2)
void trunk_kernel(const float* __restrict__ nodes, const int* __restrict__ coord_seg,
                  const float* __restrict__ tw0, const float* __restrict__ tb0,
                  const char* __restrict__ wt2_1, const float* __restrict__ tb1,
                  const char* __restrict__ wt2_2, const float* __restrict__ tb2,
                  float* __restrict__ seg_sum)
{
  __shared__ __align__(16) char act[ROWS * HH * 2];   // 32KB
  __shared__ __align__(16) char wpan[2 * PANB];       // 32KB
  const int tid = threadIdx.x;
  const int r0g = blockIdx.x * ROWS;

  layer1_mfma(act, nodes, r0g, tw0, tb0, tid);
  heavy_layer<0>(act, wpan, wt2_1, tb1, nullptr, nullptr, tid);
  heavy_layer<1>(act, wpan, wt2_2, tb2, nullptr, nullptr, tid);  // c

  // per-segment sums of c; segs sorted -> most tiles single-segment.
  {
    const int j = tid;
    const int s_lo = coord_seg[r0g];
    const int s_hi = coord_seg[r0g + ROWS - 1];
    if (s_lo == s_hi) {
      float p = 0.f;
#pragma unroll 8
      for (int r = 0; r < ROWS; ++r)
        p += (float)*(const _Float16*)(act + swz(r, j));
      atomicAdd(&seg_sum[s_lo * HH + j], p);
    } else {
      for (int s = s_lo; s <= s_hi; ++s) {
        float p = 0.f;
        for (int r = 0; r < ROWS; ++r)
          if (coord_seg[r0g + r] == s)
            p += (float)*(const _Float16*)(act + swz(r, j));
        atomicAdd(&seg_sum[s * HH + j], p);
      }
    }
  }
}

__global__ __launch_bounds__(THREADS, 2)
void branch_kernel(const float* __restrict__ known_nodes, const int* __restrict__ known_seg,
                   const float* __restrict__ bw0, const float* __restrict__ bb0,
                   const char* __restrict__ wt2_1, const float* __restrict__ bb1,
                   const char* __restrict__ wt2_2, const float* __restrict__ bb2,
                   const float* __restrict__ seg_mean,
                   const char* __restrict__ wt2_o, const float* __restrict__ ob0,
                   const float* __restrict__ ow1, const float* __restrict__ ob1,
                   float* __restrict__ out)
{
  __shared__ __align__(16) char act[ROWS * HH * 2];   // 32KB
  __shared__ __align__(16) char wpan[2 * PANB];       // 32KB
  __shared__ float ps[4 * ROWS * 3];                  // tail partials, 3KB
  const int tid = threadIdx.x;
  const int r0g = blockIdx.x * ROWS;

  layer1_mfma(act, known_nodes, r0g, bw0, bb0, tid);
  heavy_layer<0>(act, wpan, wt2_1, bb1, nullptr, nullptr, tid);
  heavy_layer<2>(act, wpan, wt2_2, bb2, seg_mean, known_seg + r0g, tid);
  heavy_layer<0>(act, wpan, wt2_o, ob0, nullptr, nullptr, tid);

  // out = h @ ow1 + ob1 (256 -> 3): 256 threads, 4 k-quarters in parallel
  {
    const int r = tid & 63;
    const int q = tid >> 6;
    float o0 = 0.f, o1 = 0.f, o2 = 0.f;
    for (int kk = 0; kk < 64; kk += 8) {
      int k0 = q * 64 + kk;
      half8 h = *(const half8*)(act + swz(r, k0));
#pragma unroll
      for (int u = 0; u < 8; ++u) {
        float a = (float)h[u];
        o0 = fmaf(a, ow1[(k0 + u) * 3 + 0], o0);
        o1 = fmaf(a, ow1[(k0 + u) * 3 + 1], o1);
        o2 = fmaf(a, ow1[(k0 + u) * 3 + 2], o2);
      }
    }
    float* p = ps + q * ROWS * 3;
    p[r * 3 + 0] = o0; p[r * 3 + 1] = o1; p[r * 3 + 2] = o2;
  }
  __syncthreads();
  if (tid < ROWS) {
    const int r = tid;
    float* dst = out + (size_t)(r0g + r) * 3;
#pragma unroll
    for (int c = 0; c < 3; ++c) {
      float o = ob1[c];
#pragma unroll
      for (int q = 0; q < 4; ++q) o += ps[q * ROWS * 3 + r * 3 + c];
      dst[c] = o;
    }
  }
}

// W[256][256] fp32 (row=k, col=j) -> WT2 panel-linear fp16:
// byte off = (k>>5)*16384 + ((k>>3)&3)*4096 + j*16 + (k&7)*2
struct WPtrs { const float* w[5]; char* wt2[5]; };
__global__ void transpose_kernel(WPtrs p)
{
  const int m = blockIdx.x >> 8;   // matrix
  const int k = blockIdx.x & 255;  // input dim
  const int j = threadIdx.x;       // output dim
  size_t off = (size_t)(k >> 5) * PANB + (size_t)((k >> 3) & 3) * 4096
             + (size_t)j * 16 + (size_t)(k & 7) * 2;
  *(_Float16*)(p.wt2[m] + off) = (_Float16)p.w[m][k * HH + j];
}

__global__ void zero_kernel(float* __restrict__ p, int n)
{
  int i = blockIdx.x * blockDim.x + threadIdx.x;
  if (i < n) p[i] = 0.f;
}

__global__ void mean_kernel(const float* __restrict__ seg_sum,
                            const int* __restrict__ coord_seg,
                            float* __restrict__ seg_mean)
{
  const int b = blockIdx.x;
  int lo = 0, n = NTOT;
  while (n > 0) { int h = n >> 1; int mid = lo + h;
    if (coord_seg[mid] < b) { lo = mid + 1; n -= h + 1; } else n = h; }
  int hi = lo; n = NTOT - lo;
  while (n > 0) { int h = n >> 1; int mid = hi + h;
    if (coord_seg[mid] < b + 1) { hi = mid + 1; n -= h + 1; } else n = h; }
  float inv = 1.0f / fmaxf((float)(hi - lo), 1.0f);
  seg_mean[b * HH + threadIdx.x] = seg_sum[b * HH + threadIdx.x] * inv;
}

// ---------------------------------------------------------------------------
extern "C" void kernel_launch(void* const* d_in, const int* in_sizes, int n_in,
                              void* d_out, int out_size, void* d_ws, size_t ws_size,
                              hipStream_t stream)
{
  const float* known_nodes = (const float*)d_in[0];
  const float* nodes       = (const float*)d_in[1];
  const int*   known_seg   = (const int*)d_in[2];
  const int*   coord_seg   = (const int*)d_in[3];
  const float* bw0 = (const float*)d_in[4];
  const float* bb0 = (const float*)d_in[5];
  const float* bw1 = (const float*)d_in[6];
  const float* bb1 = (const float*)d_in[7];
  const float* bw2 = (const float*)d_in[8];
  const float* bb2 = (const float*)d_in[9];
  const float* tw0 = (const float*)d_in[10];
  const float* tb0 = (const float*)d_in[11];
  const float* tw1 = (const float*)d_in[12];
  const float* tb1 = (const float*)d_in[13];
  const float* tw2 = (const float*)d_in[14];
  const float* tb2 = (const float*)d_in[15];
  const float* ow0 = (const float*)d_in[16];
  const float* ob0 = (const float*)d_in[17];
  const float* ow1 = (const float*)d_in[18];
  const float* ob1 = (const float*)d_in[19];

  float* out      = (float*)d_out;
  float* seg_sum  = (float*)d_ws;                        // [64][256] f32
  float* seg_mean = seg_sum + NB * HH;                   // [64][256] f32
  char* wt2b      = (char*)d_ws + (size_t)2 * NB * HH * 4;
  char* wt2_tw1 = wt2b + 0 * (size_t)HH * HH * 2;
  char* wt2_tw2 = wt2b + 1 * (size_t)HH * HH * 2;
  char* wt2_bw1 = wt2b + 2 * (size_t)HH * HH * 2;
  char* wt2_bw2 = wt2b + 3 * (size_t)HH * HH * 2;
  char* wt2_ow0 = wt2b + 4 * (size_t)HH * HH * 2;

  WPtrs wp;
  wp.w[0] = tw1; wp.wt2[0] = wt2_tw1;
  wp.w[1] = tw2; wp.wt2[1] = wt2_tw2;
  wp.w[2] = bw1; wp.wt2[2] = wt2_bw1;
  wp.w[3] = bw2; wp.wt2[3] = wt2_bw2;
  wp.w[4] = ow0; wp.wt2[4] = wt2_ow0;

  transpose_kernel<<<5 * 256, 256, 0, stream>>>(wp);
  zero_kernel<<<(NB * HH + 255) / 256, 256, 0, stream>>>(seg_sum, NB * HH);
  trunk_kernel<<<NTOT / ROWS, THREADS, 0, stream>>>(nodes, coord_seg,
                                                    tw0, tb0, wt2_tw1, tb1, wt2_tw2, tb2,
                                                    seg_sum);
  mean_kernel<<<NB, 256, 0, stream>>>(seg_sum, coord_seg, seg_mean);
  branch_kernel<<<NTOT / ROWS, THREADS, 0, stream>>>(known_nodes, known_seg,
                                                     bw0, bb0, wt2_bw1, bb1, wt2_bw2, bb2,
                                                     seg_mean,
                                                     wt2_ow0, ob0, ow1, ob1,
                                                     out);
}

// Round 11
// 258.529 us; speedup vs baseline: 1.6143x; 1.0300x over previous
//
#include <hip/hip_runtime.h>

#define HH 256       // hidden size
#define NB 64        // batch (segments)
#define ROWS 64      // rows per block tile
#define NTOT 262144  // NK == NC
#define THREADS 256  // 4 waves

typedef _Float16 half8 __attribute__((ext_vector_type(8)));
typedef _Float16 half4 __attribute__((ext_vector_type(4)));
typedef float f32x4 __attribute__((ext_vector_type(4)));

typedef __attribute__((address_space(1))) const void gas_t;
typedef __attribute__((address_space(3))) void las_t;

// act LDS tile: [row][k] fp16, 64 rows x 256 k = 32KB, row stride 512B.
__device__ __forceinline__ uint32_t swz(uint32_t r, uint32_t k) {
  return (((r << 9) + (k << 1)) ^ ((r & 7) << 4)) ^ ((r & 8) << 3);
}

// Stage one wave-private 4KB A-slab (64 j x 32 k): 4 DMA calls x 1KB.
// WT3 is pre-arranged so the copy is identity (lane-linear).
__device__ __forceinline__ void stage_slab(const char* __restrict__ g, char* l,
                                           int lane)
{
  const char* gp = g + lane * 16;
#pragma unroll
  for (int c = 0; c < 4; ++c)
    __builtin_amdgcn_global_load_lds((gas_t*)(gp + c * 1024), (las_t*)(l + c * 1024),
                                     16, 0, 0);
}

// ---------------------------------------------------------------------------
// Heavy layer via MFMA, swapped operands: D[j][r] = sum_k WT[j][k]*act[r][k]
// A comes from WAVE-PRIVATE LDS slabs staged by async DMA (double-buffered,
// counted per-wave vmcnt) -> ZERO intra-layer barriers; waves drift freely.
// Slab layout: [jf][lane][16B]; lane's A-frag = slab + jf*1024 + lane*16
// (exactly the 16B that lane DMA'd -> conflict-free, no cross-wave sharing).
// Only 2 barriers/layer: before epilogue D-writes (act still being B-read by
// other waves) and after (act complete for next layer).
// MODE: 0 relu; 1 plain (trunk c); 2 multiply seg_mean[seg_g[r]] (branch)
// ---------------------------------------------------------------------------
template<int MODE>
__device__ __forceinline__ void heavy_layer(char* act, char* wpan,
                                            const char* __restrict__ wt3,
                                            const float* __restrict__ bias,
                                            const float* __restrict__ seg_mean,
                                            const int* __restrict__ seg_g, int tid)
{
  const int wid  = tid >> 6;
  const int lane = tid & 63;
  const int lr   = lane & 15;
  const int lg   = lane >> 4;
  const int j0   = wid << 6;
  char* slab = wpan + wid * 8192;            // two private 4KB buffers
  const char* wsrc = wt3 + wid * 4096;       // + ks*16KB

  f32x4 acc[4][4];  // [jf][rf]
#pragma unroll
  for (int jf = 0; jf < 4; ++jf)
#pragma unroll
    for (int rf = 0; rf < 4; ++rf)
      acc[jf][rf] = (f32x4){0.f, 0.f, 0.f, 0.f};

  // prologue: slabs for ks=0,1 in flight (8 calls)
  stage_slab(wsrc + 0 * 16384, slab + 0 * 4096, lane);
  stage_slab(wsrc + 1 * 16384, slab + 1 * 4096, lane);

#pragma unroll
  for (int ks = 0; ks < 8; ++ks) {
    char* cur = slab + (ks & 1) * 4096;
    // wait for slab ks (the 4 calls of slab ks+1 may stay in flight)
    if (ks < 7) asm volatile("s_waitcnt vmcnt(4)" ::: "memory");
    else        asm volatile("s_waitcnt vmcnt(0)" ::: "memory");
    __builtin_amdgcn_sched_barrier(0);

    half8 b[4];
#pragma unroll
    for (int rf = 0; rf < 4; ++rf)
      b[rf] = *(const half8*)(act + swz(rf * 16 + lr, ks * 32 + lg * 8));
#pragma unroll
    for (int jf = 0; jf < 4; ++jf) {
      half8 a = *(const half8*)(cur + jf * 1024 + lane * 16);
#pragma unroll
      for (int rf = 0; rf < 4; ++rf)
        acc[jf][rf] = __builtin_amdgcn_mfma_f32_16x16x32_f16(a, b[rf], acc[jf][rf], 0, 0, 0);
    }
    // MFMA data-deps forced lgkm completion of cur's reads; pin DMA after.
    __builtin_amdgcn_sched_barrier(0);
    if (ks < 6)
      stage_slab(wsrc + (ks + 2) * 16384, cur, lane);  // refill freed buffer
  }
  // all own DMAs retired (vmcnt 0 at ks=7), all own act reads done.

  int sseg[4];
  if (MODE == 2) {
#pragma unroll
    for (int rf = 0; rf < 4; ++rf) sseg[rf] = seg_g[rf * 16 + lr];
  }

  __syncthreads();  // all waves done READING act before overwrite

#pragma unroll
  for (int jf = 0; jf < 4; ++jf) {
    f32x4 bj = *(const f32x4*)(bias + j0 + jf * 16 + lg * 4);
#pragma unroll
    for (int rf = 0; rf < 4; ++rf) {
      f32x4 v = acc[jf][rf] + bj;
      if (MODE == 2) {
        f32x4 sm = *(const f32x4*)(seg_mean + sseg[rf] * HH + j0 + jf * 16 + lg * 4);
        v *= sm;
      }
      half4 h;
#pragma unroll
      for (int u = 0; u < 4; ++u) {
        float x = v[u];
        if (MODE == 0) x = fmaxf(x, 0.f);
        h[u] = (_Float16)x;
      }
      *(half4*)(act + swz(rf * 16 + lr, j0 + jf * 16 + lg * 4)) = h;
    }
  }
  __syncthreads();  // act tile complete for next layer
}

// layer 1 via MFMA: F=3 -> H (relu), K padded 3 -> 32 with zeros.
__device__ __forceinline__ void layer1_mfma(char* act, const float* __restrict__ x,
                                            int r0g, const float* __restrict__ W0,
                                            const float* __restrict__ b0, int tid)
{
  const int wid  = tid >> 6;
  const int lane = tid & 63;
  const int lr   = lane & 15;
  const int lg   = lane >> 4;
  const int j0   = wid << 6;

  half8 a[4];
#pragma unroll
  for (int jf = 0; jf < 4; ++jf) {
    half8 v = {0, 0, 0, 0, 0, 0, 0, 0};
    if (lg == 0) {
      int j = j0 + jf * 16 + lr;
      v[0] = (_Float16)W0[j];
      v[1] = (_Float16)W0[HH + j];
      v[2] = (_Float16)W0[2 * HH + j];
    }
    a[jf] = v;
  }

  f32x4 acc[4][4];
#pragma unroll
  for (int jf = 0; jf < 4; ++jf)
#pragma unroll
    for (int rf = 0; rf < 4; ++rf)
      acc[jf][rf] = (f32x4){0.f, 0.f, 0.f, 0.f};

#pragma unroll
  for (int rf = 0; rf < 4; ++rf) {
    half8 b = {0, 0, 0, 0, 0, 0, 0, 0};
    if (lg == 0) {
      const float* xp = x + (size_t)(r0g + rf * 16 + lr) * 3;
      b[0] = (_Float16)xp[0];
      b[1] = (_Float16)xp[1];
      b[2] = (_Float16)xp[2];
    }
#pragma unroll
    for (int jf = 0; jf < 4; ++jf)
      acc[jf][rf] = __builtin_amdgcn_mfma_f32_16x16x32_f16(a[jf], b, acc[jf][rf], 0, 0, 0);
  }

#pragma unroll
  for (int jf = 0; jf < 4; ++jf) {
    f32x4 bj = *(const f32x4*)(b0 + j0 + jf * 16 + lg * 4);
#pragma unroll
    for (int rf = 0; rf < 4; ++rf) {
      f32x4 v = acc[jf][rf] + bj;
      half4 h;
#pragma unroll
      for (int u = 0; u < 4; ++u)
        h[u] = (_Float16)fmaxf(v[u], 0.f);
      *(half4*)(act + swz(rf * 16 + lr, j0 + jf * 16 + lg * 4)) = h;
    }
  }
  __syncthreads();
}

// ---------------------------------------------------------------------------
__global__ __launch_bounds__(THREADS, 2)
void trunk_kernel(const float* __restrict__ nodes, const int* __restrict__ coord_seg,
                  const float* __restrict__ tw0, const float* __restrict__ tb0,
                  const char* __restrict__ wt3_1, const float* __restrict__ tb1,
                  const char* __restrict__ wt3_2, const float* __restrict__ tb2,
                  float* __restrict__ seg_sum)
{
  __shared__ __align__(16) char act[ROWS * HH * 2];   // 32KB
  __shared__ __align__(16) char wpan[4 * 8192];       // 32KB, wave-private
  const int tid = threadIdx.x;
  const int r0g = blockIdx.x * ROWS;

  layer1_mfma(act, nodes, r0g, tw0, tb0, tid);
  heavy_layer<0>(act, wpan, wt3_1, tb1, nullptr, nullptr, tid);
  heavy_layer<1>(act, wpan, wt3_2, tb2, nullptr, nullptr, tid);  // c

  // per-segment sums of c; segs sorted -> most tiles single-segment.
  {
    const int j = tid;
    const int s_lo = coord_seg[r0g];
    const int s_hi = coord_seg[r0g + ROWS - 1];
    if (s_lo == s_hi) {
      float p = 0.f;
#pragma unroll 8
      for (int r = 0; r < ROWS; ++r)
        p += (float)*(const _Float16*)(act + swz(r, j));
      atomicAdd(&seg_sum[s_lo * HH + j], p);
    } else {
      for (int s = s_lo; s <= s_hi; ++s) {
        float p = 0.f;
        for (int r = 0; r < ROWS; ++r)
          if (coord_seg[r0g + r] == s)
            p += (float)*(const _Float16*)(act + swz(r, j));
        atomicAdd(&seg_sum[s * HH + j], p);
      }
    }
  }
}

__global__ __launch_bounds__(THREADS, 2)
void branch_kernel(const float* __restrict__ known_nodes, const int* __restrict__ known_seg,
                   const float* __restrict__ bw0, const float* __restrict__ bb0,
                   const char* __restrict__ wt3_1, const float* __restrict__ bb1,
                   const char* __restrict__ wt3_2, const float* __restrict__ bb2,
                   const float* __restrict__ seg_mean,
                   const char* __restrict__ wt3_o, const float* __restrict__ ob0,
                   const float* __restrict__ ow1, const float* __restrict__ ob1,
                   float* __restrict__ out)
{
  __shared__ __align__(16) char act[ROWS * HH * 2];   // 32KB
  __shared__ __align__(16) char wpan[4 * 8192];       // 32KB; tail reuses as ps
  const int tid = threadIdx.x;
  const int r0g = blockIdx.x * ROWS;

  layer1_mfma(act, known_nodes, r0g, bw0, bb0, tid);
  heavy_layer<0>(act, wpan, wt3_1, bb1, nullptr, nullptr, tid);
  heavy_layer<2>(act, wpan, wt3_2, bb2, seg_mean, known_seg + r0g, tid);
  heavy_layer<0>(act, wpan, wt3_o, ob0, nullptr, nullptr, tid);

  // out = h @ ow1 + ob1 (256 -> 3): 256 threads, 4 k-quarters in parallel.
  // ps reuses wpan (all DMAs retired, panel data dead).
  float* ps = (float*)wpan;
  {
    const int r = tid & 63;
    const int q = tid >> 6;
    float o0 = 0.f, o1 = 0.f, o2 = 0.f;
    for (int kk = 0; kk < 64; kk += 8) {
      int k0 = q * 64 + kk;
      half8 h = *(const half8*)(act + swz(r, k0));
#pragma unroll
      for (int u = 0; u < 8; ++u) {
        float a = (float)h[u];
        o0 = fmaf(a, ow1[(k0 + u) * 3 + 0], o0);
        o1 = fmaf(a, ow1[(k0 + u) * 3 + 1], o1);
        o2 = fmaf(a, ow1[(k0 + u) * 3 + 2], o2);
      }
    }
    float* p = ps + q * ROWS * 3;
    p[r * 3 + 0] = o0; p[r * 3 + 1] = o1; p[r * 3 + 2] = o2;
  }
  __syncthreads();
  if (tid < ROWS) {
    const int r = tid;
    float* dst = out + (size_t)(r0g + r) * 3;
#pragma unroll
    for (int c = 0; c < 3; ++c) {
      float o = ob1[c];
#pragma unroll
      for (int q = 0; q < 4; ++q) o += ps[q * ROWS * 3 + r * 3 + c];
      dst[c] = o;
    }
  }
}

// W[256][256] fp32 (row=k, col=j) -> WT3 slab-linear fp16:
// slab(ks, wq) holds j in [wq*64, wq*64+64), k in [ks*32, ks*32+32):
// off = ks*16KB + wq*4KB + jf*1KB + (lg*16+lr)*16 + kk*2
//   where jf=(j>>4)&3, lr=j&15, lg=(k>>3)&3, kk=k&7.
struct WPtrs { const float* w[5]; char* wt3[5]; };
__global__ void transpose_kernel(WPtrs p)
{
  const int m = blockIdx.x >> 8;   // matrix
  const int k = blockIdx.x & 255;  // input dim
  const int j = threadIdx.x;       // output dim
  size_t off = (size_t)(k >> 5) * 16384 + (size_t)(j >> 6) * 4096
             + (size_t)((j >> 4) & 3) * 1024
             + (size_t)((((k >> 3) & 3) << 4) | (j & 15)) * 16
             + (size_t)(k & 7) * 2;
  *(_Float16*)(p.wt3[m] + off) = (_Float16)p.w[m][k * HH + j];
}

__global__ void zero_kernel(float* __restrict__ p, int n)
{
  int i = blockIdx.x * blockDim.x + threadIdx.x;
  if (i < n) p[i] = 0.f;
}

__global__ void mean_kernel(const float* __restrict__ seg_sum,
                            const int* __restrict__ coord_seg,
                            float* __restrict__ seg_mean)
{
  const int b = blockIdx.x;
  int lo = 0, n = NTOT;
  while (n > 0) { int h = n >> 1; int mid = lo + h;
    if (coord_seg[mid] < b) { lo = mid + 1; n -= h + 1; } else n = h; }
  int hi = lo; n = NTOT - lo;
  while (n > 0) { int h = n >> 1; int mid = hi + h;
    if (coord_seg[mid] < b + 1) { hi = mid + 1; n -= h + 1; } else n = h; }
  float inv = 1.0f / fmaxf((float)(hi - lo), 1.0f);
  seg_mean[b * HH + threadIdx.x] = seg_sum[b * HH + threadIdx.x] * inv;
}

// ---------------------------------------------------------------------------
extern "C" void kernel_launch(void* const* d_in, const int* in_sizes, int n_in,
                              void* d_out, int out_size, void* d_ws, size_t ws_size,
                              hipStream_t stream)
{
  const float* known_nodes = (const float*)d_in[0];
  const float* nodes       = (const float*)d_in[1];
  const int*   known_seg   = (const int*)d_in[2];
  const int*   coord_seg   = (const int*)d_in[3];
  const float* bw0 = (const float*)d_in[4];
  const float* bb0 = (const float*)d_in[5];
  const float* bw1 = (const float*)d_in[6];
  const float* bb1 = (const float*)d_in[7];
  const float* bw2 = (const float*)d_in[8];
  const float* bb2 = (const float*)d_in[9];
  const float* tw0 = (const float*)d_in[10];
  const float* tb0 = (const float*)d_in[11];
  const float* tw1 = (const float*)d_in[12];
  const float* tb1 = (const float*)d_in[13];
  const float* tw2 = (const float*)d_in[14];
  const float* tb2 = (const float*)d_in[15];
  const float* ow0 = (const float*)d_in[16];
  const float* ob0 = (const float*)d_in[17];
  const float* ow1 = (const float*)d_in[18];
  const float* ob1 = (const float*)d_in[19];

  float* out      = (float*)d_out;
  float* seg_sum  = (float*)d_ws;                        // [64][256] f32
  float* seg_mean = seg_sum + NB * HH;                   // [64][256] f32
  char* wt3b      = (char*)d_ws + (size_t)2 * NB * HH * 4;
  char* wt3_tw1 = wt3b + 0 * (size_t)HH * HH * 2;
  char* wt3_tw2 = wt3b + 1 * (size_t)HH * HH * 2;
  char* wt3_bw1 = wt3b + 2 * (size_t)HH * HH * 2;
  char* wt3_bw2 = wt3b + 3 * (size_t)HH * HH * 2;
  char* wt3_ow0 = wt3b + 4 * (size_t)HH * HH * 2;

  WPtrs wp;
  wp.w[0] = tw1; wp.wt3[0] = wt3_tw1;
  wp.w[1] = tw2; wp.wt3[1] = wt3_tw2;
  wp.w[2] = bw1; wp.wt3[2] = wt3_bw1;
  wp.w[3] = bw2; wp.wt3[3] = wt3_bw2;
  wp.w[4] = ow0; wp.wt3[4] = wt3_ow0;

  transpose_kernel<<<5 * 256, 256, 0, stream>>>(wp);
  zero_kernel<<<(NB * HH + 255) / 256, 256, 0, stream>>>(seg_sum, NB * HH);
  trunk_kernel<<<NTOT / ROWS, THREADS, 0, stream>>>(nodes, coord_seg,
                                                    tw0, tb0, wt3_tw1, tb1, wt3_tw2, tb2,
                                                    seg_sum);
  mean_kernel<<<NB, 256, 0, stream>>>(seg_sum, coord_seg, seg_mean);
  branch_kernel<<<NTOT / ROWS, THREADS, 0, stream>>>(known_nodes, known_seg,
                                                     bw0, bb0, wt3_bw1, bb1, wt3_bw2, bb2,
                                                     seg_mean,
                                                     wt3_ow0, ob0, ow1, ob1,
                                                     out);
}

// Round 12
// 254.367 us; speedup vs baseline: 1.6408x; 1.0164x over previous
//
#include <hip/hip_runtime.h>

#define HH 256       // hidden size
#define NB 64        // batch (segments)
#define ROWS 64      // rows per block tile
#define NTOT 262144  // NK == NC
#define THREADS 256  // 4 waves

typedef _Float16 half8 __attribute__((ext_vector_type(8)));
typedef _Float16 half4 __attribute__((ext_vector_type(4)));
typedef float f32x4 __attribute__((ext_vector_type(4)));

typedef __attribute__((address_space(1))) const void gas_t;
typedef __attribute__((address_space(3))) void las_t;

// act LDS tile: [row][k] fp16, 64 rows x 256 k = 32KB, row stride 512B.
__device__ __forceinline__ uint32_t swz(uint32_t r, uint32_t k) {
  return (((r << 9) + (k << 1)) ^ ((r & 7) << 4)) ^ ((r & 8) << 3);
}

// Stage one wave-private 4KB A-slab (64 j x 32 k): 4 DMA calls x 1KB.
// WT3 is pre-arranged so the copy is identity (lane-linear).
__device__ __forceinline__ void stage_slab(const char* __restrict__ g, char* l,
                                           int lane)
{
  const char* gp = g + lane * 16;
#pragma unroll
  for (int c = 0; c < 4; ++c)
    __builtin_amdgcn_global_load_lds((gas_t*)(gp + c * 1024), (las_t*)(l + c * 1024),
                                     16, 0, 0);
}

// ---------------------------------------------------------------------------
// Heavy layer via MFMA, swapped operands: D[j][r] = sum_k WT[j][k]*act[r][k]
// A from WAVE-PRIVATE LDS slabs, async DMA, *** 3-deep pipeline ***:
// slab ks is consumed while slabs ks+1, ks+2 are in flight (wait vmcnt(8)) ->
// each slab gets ~2 ks-steps (~500cy) of L2-latency cover. Zero intra-layer
// barriers (vmcnt is per-wave); 2 barriers/layer around the act overwrite.
// MODE: 0 relu; 1 plain (trunk c); 2 multiply seg_mean[seg_g[r]] (branch)
// ---------------------------------------------------------------------------
template<int MODE>
__device__ __forceinline__ void heavy_layer(char* act, char* wpan,
                                            const char* __restrict__ wt3,
                                            const float* __restrict__ bias,
                                            const float* __restrict__ seg_mean,
                                            const int* __restrict__ seg_g, int tid)
{
  const int wid  = tid >> 6;
  const int lane = tid & 63;
  const int lr   = lane & 15;
  const int lg   = lane >> 4;
  const int j0   = wid << 6;
  char* slab = wpan + wid * 12288;           // three private 4KB buffers
  const char* wsrc = wt3 + wid * 4096;       // + ks*16KB

  f32x4 acc[4][4];  // [jf][rf]
#pragma unroll
  for (int jf = 0; jf < 4; ++jf)
#pragma unroll
    for (int rf = 0; rf < 4; ++rf)
      acc[jf][rf] = (f32x4){0.f, 0.f, 0.f, 0.f};

  // prologue: slabs for ks=0,1,2 in flight (12 calls)
  stage_slab(wsrc + 0 * 16384, slab + 0 * 4096, lane);
  stage_slab(wsrc + 1 * 16384, slab + 1 * 4096, lane);
  stage_slab(wsrc + 2 * 16384, slab + 2 * 4096, lane);

#pragma unroll
  for (int ks = 0; ks < 8; ++ks) {
    char* cur = slab + (ks % 3) * 4096;
    // wait for slab ks; slabs ks+1, ks+2 (8 calls) may stay in flight
    if (ks < 6)      asm volatile("s_waitcnt vmcnt(8)" ::: "memory");
    else if (ks == 6) asm volatile("s_waitcnt vmcnt(4)" ::: "memory");
    else              asm volatile("s_waitcnt vmcnt(0)" ::: "memory");
    __builtin_amdgcn_sched_barrier(0);

    half8 b[4];
#pragma unroll
    for (int rf = 0; rf < 4; ++rf)
      b[rf] = *(const half8*)(act + swz(rf * 16 + lr, ks * 32 + lg * 8));
#pragma unroll
    for (int jf = 0; jf < 4; ++jf) {
      half8 a = *(const half8*)(cur + jf * 1024 + lane * 16);
#pragma unroll
      for (int rf = 0; rf < 4; ++rf)
        acc[jf][rf] = __builtin_amdgcn_mfma_f32_16x16x32_f16(a, b[rf], acc[jf][rf], 0, 0, 0);
    }
    // MFMA data-deps forced lgkm completion of cur's reads; pin DMA after.
    __builtin_amdgcn_sched_barrier(0);
    if (ks < 5)
      stage_slab(wsrc + (ks + 3) * 16384, cur, lane);  // refill freed buffer
  }
  // all own DMAs retired (vmcnt 0 at ks=7), all own act reads done.

  int sseg[4];
  if (MODE == 2) {
#pragma unroll
    for (int rf = 0; rf < 4; ++rf) sseg[rf] = seg_g[rf * 16 + lr];
  }

  __syncthreads();  // all waves done READING act before overwrite

#pragma unroll
  for (int jf = 0; jf < 4; ++jf) {
    f32x4 bj = *(const f32x4*)(bias + j0 + jf * 16 + lg * 4);
#pragma unroll
    for (int rf = 0; rf < 4; ++rf) {
      f32x4 v = acc[jf][rf] + bj;
      if (MODE == 2) {
        f32x4 sm = *(const f32x4*)(seg_mean + sseg[rf] * HH + j0 + jf * 16 + lg * 4);
        v *= sm;
      }
      half4 h;
#pragma unroll
      for (int u = 0; u < 4; ++u) {
        float x = v[u];
        if (MODE == 0) x = fmaxf(x, 0.f);
        h[u] = (_Float16)x;
      }
      *(half4*)(act + swz(rf * 16 + lr, j0 + jf * 16 + lg * 4)) = h;
    }
  }
  __syncthreads();  // act tile complete for next layer
}

// layer 1 via MFMA: F=3 -> H (relu), K padded 3 -> 32 with zeros.
__device__ __forceinline__ void layer1_mfma(char* act, const float* __restrict__ x,
                                            int r0g, const float* __restrict__ W0,
                                            const float* __restrict__ b0, int tid)
{
  const int wid  = tid >> 6;
  const int lane = tid & 63;
  const int lr   = lane & 15;
  const int lg   = lane >> 4;
  const int j0   = wid << 6;

  half8 a[4];
#pragma unroll
  for (int jf = 0; jf < 4; ++jf) {
    half8 v = {0, 0, 0, 0, 0, 0, 0, 0};
    if (lg == 0) {
      int j = j0 + jf * 16 + lr;
      v[0] = (_Float16)W0[j];
      v[1] = (_Float16)W0[HH + j];
      v[2] = (_Float16)W0[2 * HH + j];
    }
    a[jf] = v;
  }

  f32x4 acc[4][4];
#pragma unroll
  for (int jf = 0; jf < 4; ++jf)
#pragma unroll
    for (int rf = 0; rf < 4; ++rf)
      acc[jf][rf] = (f32x4){0.f, 0.f, 0.f, 0.f};

#pragma unroll
  for (int rf = 0; rf < 4; ++rf) {
    half8 b = {0, 0, 0, 0, 0, 0, 0, 0};
    if (lg == 0) {
      const float* xp = x + (size_t)(r0g + rf * 16 + lr) * 3;
      b[0] = (_Float16)xp[0];
      b[1] = (_Float16)xp[1];
      b[2] = (_Float16)xp[2];
    }
#pragma unroll
    for (int jf = 0; jf < 4; ++jf)
      acc[jf][rf] = __builtin_amdgcn_mfma_f32_16x16x32_f16(a[jf], b, acc[jf][rf], 0, 0, 0);
  }

#pragma unroll
  for (int jf = 0; jf < 4; ++jf) {
    f32x4 bj = *(const f32x4*)(b0 + j0 + jf * 16 + lg * 4);
#pragma unroll
    for (int rf = 0; rf < 4; ++rf) {
      f32x4 v = acc[jf][rf] + bj;
      half4 h;
#pragma unroll
      for (int u = 0; u < 4; ++u)
        h[u] = (_Float16)fmaxf(v[u], 0.f);
      *(half4*)(act + swz(rf * 16 + lr, j0 + jf * 16 + lg * 4)) = h;
    }
  }
  __syncthreads();
}

// ---------------------------------------------------------------------------
__global__ __launch_bounds__(THREADS, 2)
void trunk_kernel(const float* __restrict__ nodes, const int* __restrict__ coord_seg,
                  const float* __restrict__ tw0, const float* __restrict__ tb0,
                  const char* __restrict__ wt3_1, const float* __restrict__ tb1,
                  const char* __restrict__ wt3_2, const float* __restrict__ tb2,
                  float* __restrict__ seg_sum)
{
  __shared__ __align__(16) char act[ROWS * HH * 2];   // 32KB
  __shared__ __align__(16) char wpan[4 * 12288];      // 48KB, wave-private x3
  const int tid = threadIdx.x;
  const int r0g = blockIdx.x * ROWS;

  layer1_mfma(act, nodes, r0g, tw0, tb0, tid);
  heavy_layer<0>(act, wpan, wt3_1, tb1, nullptr, nullptr, tid);
  heavy_layer<1>(act, wpan, wt3_2, tb2, nullptr, nullptr, tid);  // c

  // per-segment sums of c; segs sorted -> most tiles single-segment.
  {
    const int j = tid;
    const int s_lo = coord_seg[r0g];
    const int s_hi = coord_seg[r0g + ROWS - 1];
    if (s_lo == s_hi) {
      float p = 0.f;
#pragma unroll 8
      for (int r = 0; r < ROWS; ++r)
        p += (float)*(const _Float16*)(act + swz(r, j));
      atomicAdd(&seg_sum[s_lo * HH + j], p);
    } else {
      for (int s = s_lo; s <= s_hi; ++s) {
        float p = 0.f;
        for (int r = 0; r < ROWS; ++r)
          if (coord_seg[r0g + r] == s)
            p += (float)*(const _Float16*)(act + swz(r, j));
        atomicAdd(&seg_sum[s * HH + j], p);
      }
    }
  }
}

__global__ __launch_bounds__(THREADS, 2)
void branch_kernel(const float* __restrict__ known_nodes, const int* __restrict__ known_seg,
                   const float* __restrict__ bw0, const float* __restrict__ bb0,
                   const char* __restrict__ wt3_1, const float* __restrict__ bb1,
                   const char* __restrict__ wt3_2, const float* __restrict__ bb2,
                   const float* __restrict__ seg_mean,
                   const char* __restrict__ wt3_o, const float* __restrict__ ob0,
                   const float* __restrict__ ow1, const float* __restrict__ ob1,
                   float* __restrict__ out)
{
  __shared__ __align__(16) char act[ROWS * HH * 2];   // 32KB
  __shared__ __align__(16) char wpan[4 * 12288];      // 48KB; tail reuses as ps
  const int tid = threadIdx.x;
  const int r0g = blockIdx.x * ROWS;

  layer1_mfma(act, known_nodes, r0g, bw0, bb0, tid);
  heavy_layer<0>(act, wpan, wt3_1, bb1, nullptr, nullptr, tid);
  heavy_layer<2>(act, wpan, wt3_2, bb2, seg_mean, known_seg + r0g, tid);
  heavy_layer<0>(act, wpan, wt3_o, ob0, nullptr, nullptr, tid);

  // out = h @ ow1 + ob1 (256 -> 3): 256 threads, 4 k-quarters in parallel.
  // ps reuses wpan (all DMAs retired, panel data dead).
  float* ps = (float*)wpan;
  {
    const int r = tid & 63;
    const int q = tid >> 6;
    float o0 = 0.f, o1 = 0.f, o2 = 0.f;
    for (int kk = 0; kk < 64; kk += 8) {
      int k0 = q * 64 + kk;
      half8 h = *(const half8*)(act + swz(r, k0));
#pragma unroll
      for (int u = 0; u < 8; ++u) {
        float a = (float)h[u];
        o0 = fmaf(a, ow1[(k0 + u) * 3 + 0], o0);
        o1 = fmaf(a, ow1[(k0 + u) * 3 + 1], o1);
        o2 = fmaf(a, ow1[(k0 + u) * 3 + 2], o2);
      }
    }
    float* p = ps + q * ROWS * 3;
    p[r * 3 + 0] = o0; p[r * 3 + 1] = o1; p[r * 3 + 2] = o2;
  }
  __syncthreads();
  if (tid < ROWS) {
    const int r = tid;
    float* dst = out + (size_t)(r0g + r) * 3;
#pragma unroll
    for (int c = 0; c < 3; ++c) {
      float o = ob1[c];
#pragma unroll
      for (int q = 0; q < 4; ++q) o += ps[q * ROWS * 3 + r * 3 + c];
      dst[c] = o;
    }
  }
}

// W[256][256] fp32 (row=k, col=j) -> WT3 slab-linear fp16:
// slab(ks, wq) holds j in [wq*64, wq*64+64), k in [ks*32, ks*32+32):
// off = ks*16KB + wq*4KB + jf*1KB + (lg*16+lr)*16 + kk*2
//   where jf=(j>>4)&3, lr=j&15, lg=(k>>3)&3, kk=k&7.
struct WPtrs { const float* w[5]; char* wt3[5]; };
__global__ void transpose_kernel(WPtrs p)
{
  const int m = blockIdx.x >> 8;   // matrix
  const int k = blockIdx.x & 255;  // input dim
  const int j = threadIdx.x;       // output dim
  size_t off = (size_t)(k >> 5) * 16384 + (size_t)(j >> 6) * 4096
             + (size_t)((j >> 4) & 3) * 1024
             + (size_t)((((k >> 3) & 3) << 4) | (j & 15)) * 16
             + (size_t)(k & 7) * 2;
  *(_Float16*)(p.wt3[m] + off) = (_Float16)p.w[m][k * HH + j];
}

__global__ void zero_kernel(float* __restrict__ p, int n)
{
  int i = blockIdx.x * blockDim.x + threadIdx.x;
  if (i < n) p[i] = 0.f;
}

__global__ void mean_kernel(const float* __restrict__ seg_sum,
                            const int* __restrict__ coord_seg,
                            float* __restrict__ seg_mean)
{
  const int b = blockIdx.x;
  int lo = 0, n = NTOT;
  while (n > 0) { int h = n >> 1; int mid = lo + h;
    if (coord_seg[mid] < b) { lo = mid + 1; n -= h + 1; } else n = h; }
  int hi = lo; n = NTOT - lo;
  while (n > 0) { int h = n >> 1; int mid = hi + h;
    if (coord_seg[mid] < b + 1) { hi = mid + 1; n -= h + 1; } else n = h; }
  float inv = 1.0f / fmaxf((float)(hi - lo), 1.0f);
  seg_mean[b * HH + threadIdx.x] = seg_sum[b * HH + threadIdx.x] * inv;
}

// ---------------------------------------------------------------------------
extern "C" void kernel_launch(void* const* d_in, const int* in_sizes, int n_in,
                              void* d_out, int out_size, void* d_ws, size_t ws_size,
                              hipStream_t stream)
{
  const float* known_nodes = (const float*)d_in[0];
  const float* nodes       = (const float*)d_in[1];
  const int*   known_seg   = (const int*)d_in[2];
  const int*   coord_seg   = (const int*)d_in[3];
  const float* bw0 = (const float*)d_in[4];
  const float* bb0 = (const float*)d_in[5];
  const float* bw1 = (const float*)d_in[6];
  const float* bb1 = (const float*)d_in[7];
  const float* bw2 = (const float*)d_in[8];
  const float* bb2 = (const float*)d_in[9];
  const float* tw0 = (const float*)d_in[10];
  const float* tb0 = (const float*)d_in[11];
  const float* tw1 = (const float*)d_in[12];
  const float* tb1 = (const float*)d_in[13];
  const float* tw2 = (const float*)d_in[14];
  const float* tb2 = (const float*)d_in[15];
  const float* ow0 = (const float*)d_in[16];
  const float* ob0 = (const float*)d_in[17];
  const float* ow1 = (const float*)d_in[18];
  const float* ob1 = (const float*)d_in[19];

  float* out      = (float*)d_out;
  float* seg_sum  = (float*)d_ws;                        // [64][256] f32
  float* seg_mean = seg_sum + NB * HH;                   // [64][256] f32
  char* wt3b      = (char*)d_ws + (size_t)2 * NB * HH * 4;
  char* wt3_tw1 = wt3b + 0 * (size_t)HH * HH * 2;
  char* wt3_tw2 = wt3b + 1 * (size_t)HH * HH * 2;
  char* wt3_bw1 = wt3b + 2 * (size_t)HH * HH * 2;
  char* wt3_bw2 = wt3b + 3 * (size_t)HH * HH * 2;
  char* wt3_ow0 = wt3b + 4 * (size_t)HH * HH * 2;

  WPtrs wp;
  wp.w[0] = tw1; wp.wt3[0] = wt3_tw1;
  wp.w[1] = tw2; wp.wt3[1] = wt3_tw2;
  wp.w[2] = bw1; wp.wt3[2] = wt3_bw1;
  wp.w[3] = bw2; wp.wt3[3] = wt3_bw2;
  wp.w[4] = ow0; wp.wt3[4] = wt3_ow0;

  transpose_kernel<<<5 * 256, 256, 0, stream>>>(wp);
  zero_kernel<<<(NB * HH + 255) / 256, 256, 0, stream>>>(seg_sum, NB * HH);
  trunk_kernel<<<NTOT / ROWS, THREADS, 0, stream>>>(nodes, coord_seg,
                                                    tw0, tb0, wt3_tw1, tb1, wt3_tw2, tb2,
                                                    seg_sum);
  mean_kernel<<<NB, 256, 0, stream>>>(seg_sum, coord_seg, seg_mean);
  branch_kernel<<<NTOT / ROWS, THREADS, 0, stream>>>(known_nodes, known_seg,
                                                     bw0, bb0, wt3_bw1, bb1, wt3_bw2, bb2,
                                                     seg_mean,
                                                     wt3_ow0, ob0, ow1, ob1,
                                                     out);
}